// Round 1
// baseline (405.316 us; speedup 1.0000x reference)
//
#include <hip/hip_runtime.h>

// gridPooling: scatter-max of per-point features into a voxel grid.
// Strategy: CSR binning (count -> scan -> scatter) then gather-max with
// full-line coalesced output writes. No atomics in the hot pass.

__global__ __launch_bounds__(256) void k_count(
    const float* __restrict__ pts, int* __restrict__ cellId,
    int* __restrict__ counts, int BN, int N, int HD, int Dd, int WHD,
    float fW, float fH, float fD, int Wm1, int Hm1, int Dm1)
{
    int i = blockIdx.x * 256 + threadIdx.x;
    if (i >= BN) return;
    float x = pts[3 * i + 0];
    float y = pts[3 * i + 1];
    float z = pts[3 * i + 2];
    int ix = (int)floorf(x * fW); ix = ix < 0 ? 0 : (ix > Wm1 ? Wm1 : ix);
    int iy = (int)floorf(y * fH); iy = iy < 0 ? 0 : (iy > Hm1 ? Hm1 : iy);
    int iz = (int)floorf(z * fD); iz = iz < 0 ? 0 : (iz > Dm1 ? Dm1 : iz);
    int b = i / N;
    int seg = b * WHD + ix * HD + iy * Dd + iz;
    cellId[i] = seg;
    atomicAdd(&counts[seg], 1);
}

// Block-local exclusive scan (256 elems/block); block totals to blockSums.
__global__ __launch_bounds__(256) void k_scan1(
    const int* __restrict__ counts, int* __restrict__ excl,
    int* __restrict__ blockSums, int n)
{
    __shared__ int lds[256];
    int tid = threadIdx.x;
    int i = blockIdx.x * 256 + tid;
    int v = (i < n) ? counts[i] : 0;
    lds[tid] = v;
    __syncthreads();
    for (int off = 1; off < 256; off <<= 1) {
        int t = (tid >= off) ? lds[tid - off] : 0;
        __syncthreads();
        lds[tid] += t;
        __syncthreads();
    }
    int incl = lds[tid];
    if (i < n) excl[i] = incl - v;
    if (tid == 255) blockSums[blockIdx.x] = incl;
}

// Single-block exclusive scan of block sums (serial over 256-wide chunks).
__global__ __launch_bounds__(256) void k_scan2(int* __restrict__ blockSums, int nb)
{
    __shared__ int lds[256];
    __shared__ int carryS;
    int tid = threadIdx.x;
    if (tid == 0) carryS = 0;
    __syncthreads();
    int nChunks = (nb + 255) / 256;
    for (int ch = 0; ch < nChunks; ++ch) {
        int i = ch * 256 + tid;
        int v = (i < nb) ? blockSums[i] : 0;
        lds[tid] = v;
        __syncthreads();
        for (int off = 1; off < 256; off <<= 1) {
            int t = (tid >= off) ? lds[tid - off] : 0;
            __syncthreads();
            lds[tid] += t;
            __syncthreads();
        }
        int incl = lds[tid];
        int base = carryS;
        __syncthreads();               // everyone read carryS before update
        if (i < nb) blockSums[i] = base + incl - v;
        if (tid == 255) carryS = base + incl;
        __syncthreads();
    }
}

__global__ __launch_bounds__(256) void k_scan3(
    int* __restrict__ excl, const int* __restrict__ blockSums,
    int* __restrict__ cur, int n, int total)
{
    int i = blockIdx.x * 256 + threadIdx.x;
    if (i < n) {
        int o = excl[i] + blockSums[blockIdx.x];
        excl[i] = o;
        cur[i] = o;
    }
    if (i == 0) excl[n] = total;
}

__global__ __launch_bounds__(256) void k_scatter(
    const int* __restrict__ cellId, int* __restrict__ cur,
    int* __restrict__ ptIdx, int BN)
{
    int i = blockIdx.x * 256 + threadIdx.x;
    if (i >= BN) return;
    int seg = cellId[i];
    int pos = atomicAdd(&cur[seg], 1);
    ptIdx[pos] = i;   // global point index; feat row = i
}

// One workgroup per (batch, line of 16 consecutive cells). Thread c owns
// channel c: max-reduce over points binned into those cells, then write a
// full 64B line of out[b][c][line*16 .. line*16+15].
__global__ __launch_bounds__(256) void k_pool(
    const float* __restrict__ feat, const int* __restrict__ offsets,
    const int* __restrict__ ptIdx, float* __restrict__ out,
    int C, int WHD)
{
    int line = blockIdx.x;
    int b = blockIdx.y;
    int c = threadIdx.x;
    __shared__ int offs[17];
    int segBase = b * WHD + line * 16;
    if (threadIdx.x < 17) offs[threadIdx.x] = offsets[segBase + threadIdx.x];
    __syncthreads();
    float m[16];
#pragma unroll
    for (int j = 0; j < 16; ++j) m[j] = 0.0f;
#pragma unroll
    for (int j = 0; j < 16; ++j) {
        int e = offs[j + 1];
        for (int p = offs[j]; p < e; ++p) {
            int pi = ptIdx[p];
            float v = feat[(size_t)pi * C + c];
            m[j] = fmaxf(m[j], v);
        }
    }
    size_t ob = ((size_t)(b * C + c)) * (size_t)WHD + (size_t)line * 16;
    float4* o4 = reinterpret_cast<float4*>(out + ob);
    o4[0] = make_float4(m[0],  m[1],  m[2],  m[3]);
    o4[1] = make_float4(m[4],  m[5],  m[6],  m[7]);
    o4[2] = make_float4(m[8],  m[9],  m[10], m[11]);
    o4[3] = make_float4(m[12], m[13], m[14], m[15]);
}

extern "C" void kernel_launch(void* const* d_in, const int* in_sizes, int n_in,
                              void* d_out, int out_size, void* d_ws, size_t ws_size,
                              hipStream_t stream)
{
    const float* feat = (const float*)d_in[0];
    const float* pts  = (const float*)d_in[1];

    int BN  = in_sizes[1] / 3;           // B*N
    int C   = in_sizes[0] / BN;          // 256
    const int W = 32, H = 32, Dd = 32;   // fixed by setup_inputs
    int WHD = W * H * Dd;                // 32768
    int B   = out_size / (C * WHD);      // 16
    int N   = BN / B;                    // 8192
    int NSEG = B * WHD;                  // 524288
    int nBlocksScan = (NSEG + 255) / 256;

    char* w = (char*)d_ws;
    auto alloc = [&](size_t bytes) -> void* {
        void* p = (void*)w;
        w += ((bytes + 255) / 256) * 256;
        return p;
    };
    int* cellId    = (int*)alloc((size_t)BN * 4);
    int* counts    = (int*)alloc((size_t)NSEG * 4);
    int* offsets   = (int*)alloc(((size_t)NSEG + 1) * 4);
    int* cur       = (int*)alloc((size_t)NSEG * 4);
    int* blockSums = (int*)alloc((size_t)nBlocksScan * 4);
    int* ptIdx     = (int*)alloc((size_t)BN * 4);
    (void)ws_size;

    hipMemsetAsync(counts, 0, (size_t)NSEG * 4, stream);

    k_count<<<(BN + 255) / 256, 256, 0, stream>>>(
        pts, cellId, counts, BN, N, H * Dd, Dd, WHD,
        (float)W, (float)H, (float)Dd, W - 1, H - 1, Dd - 1);

    k_scan1<<<nBlocksScan, 256, 0, stream>>>(counts, offsets, blockSums, NSEG);
    k_scan2<<<1, 256, 0, stream>>>(blockSums, nBlocksScan);
    k_scan3<<<nBlocksScan, 256, 0, stream>>>(offsets, blockSums, cur, NSEG, BN);

    k_scatter<<<(BN + 255) / 256, 256, 0, stream>>>(cellId, cur, ptIdx, BN);

    dim3 g(WHD / 16, B);
    k_pool<<<g, C, 0, stream>>>(feat, offsets, ptIdx, (float*)d_out, C, WHD);
}

// Round 2
// 294.378 us; speedup vs baseline: 1.3769x; 1.3769x over previous
//
#include <hip/hip_runtime.h>

// gridPooling: scatter-max of per-point features into a voxel grid.
// CSR binning (count -> scan -> scatter), then a tiled gather-max:
// block = (batch, 512 consecutive cells, 16-channel chunk), LDS tile
// [16][512] with float-as-int atomicMax, contiguous 2KB-per-channel
// streaming writes. Fixes the R1 bottleneck (128KB-strided scattered
// 16B writes -> 20% HBM peak).

#define CELLS_PER_BLK 512
#define CH_PER_BLK    16

__global__ __launch_bounds__(256) void k_count(
    const float* __restrict__ pts, int* __restrict__ cellId,
    int* __restrict__ counts, int BN, int N, int HD, int Dd, int WHD,
    float fW, float fH, float fD, int Wm1, int Hm1, int Dm1)
{
    int i = blockIdx.x * 256 + threadIdx.x;
    if (i >= BN) return;
    float x = pts[3 * i + 0];
    float y = pts[3 * i + 1];
    float z = pts[3 * i + 2];
    int ix = (int)floorf(x * fW); ix = ix < 0 ? 0 : (ix > Wm1 ? Wm1 : ix);
    int iy = (int)floorf(y * fH); iy = iy < 0 ? 0 : (iy > Hm1 ? Hm1 : iy);
    int iz = (int)floorf(z * fD); iz = iz < 0 ? 0 : (iz > Dm1 ? Dm1 : iz);
    int b = i / N;
    int seg = b * WHD + ix * HD + iy * Dd + iz;
    cellId[i] = seg;
    atomicAdd(&counts[seg], 1);
}

// Block-local exclusive scan (256 elems/block); block totals to blockSums.
__global__ __launch_bounds__(256) void k_scan1(
    const int* __restrict__ counts, int* __restrict__ excl,
    int* __restrict__ blockSums, int n)
{
    __shared__ int lds[256];
    int tid = threadIdx.x;
    int i = blockIdx.x * 256 + tid;
    int v = (i < n) ? counts[i] : 0;
    lds[tid] = v;
    __syncthreads();
    for (int off = 1; off < 256; off <<= 1) {
        int t = (tid >= off) ? lds[tid - off] : 0;
        __syncthreads();
        lds[tid] += t;
        __syncthreads();
    }
    int incl = lds[tid];
    if (i < n) excl[i] = incl - v;
    if (tid == 255) blockSums[blockIdx.x] = incl;
}

// Single-block exclusive scan of block sums (serial over 256-wide chunks).
__global__ __launch_bounds__(256) void k_scan2(int* __restrict__ blockSums, int nb)
{
    __shared__ int lds[256];
    __shared__ int carryS;
    int tid = threadIdx.x;
    if (tid == 0) carryS = 0;
    __syncthreads();
    int nChunks = (nb + 255) / 256;
    for (int ch = 0; ch < nChunks; ++ch) {
        int i = ch * 256 + tid;
        int v = (i < nb) ? blockSums[i] : 0;
        lds[tid] = v;
        __syncthreads();
        for (int off = 1; off < 256; off <<= 1) {
            int t = (tid >= off) ? lds[tid - off] : 0;
            __syncthreads();
            lds[tid] += t;
            __syncthreads();
        }
        int incl = lds[tid];
        int base = carryS;
        __syncthreads();               // everyone read carryS before update
        if (i < nb) blockSums[i] = base + incl - v;
        if (tid == 255) carryS = base + incl;
        __syncthreads();
    }
}

__global__ __launch_bounds__(256) void k_scan3(
    int* __restrict__ excl, const int* __restrict__ blockSums,
    int* __restrict__ cur, int n, int total)
{
    int i = blockIdx.x * 256 + threadIdx.x;
    if (i < n) {
        int o = excl[i] + blockSums[blockIdx.x];
        excl[i] = o;
        cur[i] = o;
    }
    if (i == 0) excl[n] = total;
}

__global__ __launch_bounds__(256) void k_scatter(
    const int* __restrict__ cellId, int* __restrict__ cur,
    int* __restrict__ ptIdx, int* __restrict__ sortedCell, int BN)
{
    int i = blockIdx.x * 256 + threadIdx.x;
    if (i >= BN) return;
    int seg = cellId[i];
    int pos = atomicAdd(&cur[seg], 1);
    ptIdx[pos] = i;        // global point index; feat row = i
    sortedCell[pos] = seg; // cell id, sorted order
}

// Block = (cellBlock of 512 cells, 16-channel chunk, batch).
// Points for the cell range are a contiguous slice of ptIdx (CSR-sorted).
// Gather: 16-lane subgroups read 16 consecutive channels per point (64B,
// each feat line fetched exactly once) and atomicMax into an LDS tile.
// Float-as-int atomicMax is exact: values are max(0,v) >= 0, so int
// ordering == float ordering. XOR swizzle (cell ^ (c<<2)) breaks the
// 16-way stride-512 bank conflict while keeping float4 runs contiguous.
// Write-out: 2KB contiguous per channel, 1KB per wave store instruction.
__global__ __launch_bounds__(256) void k_pool(
    const float* __restrict__ feat, const int* __restrict__ offsets,
    const int* __restrict__ ptIdx, const int* __restrict__ sortedCell,
    float* __restrict__ out, int C, int WHD)
{
    __shared__ int lds[CH_PER_BLK * CELLS_PER_BLK];
    int cb = blockIdx.x, chunk = blockIdx.y, b = blockIdx.z;
    int segBase = b * WHD + cb * CELLS_PER_BLK;

    for (int i = threadIdx.x; i < CH_PER_BLK * CELLS_PER_BLK; i += 256)
        lds[i] = 0;
    __syncthreads();

    int p0 = offsets[segBase];                      // block-uniform -> scalar
    int p1 = offsets[segBase + CELLS_PER_BLK];
    int tSub  = threadIdx.x >> 4;                   // 16 point slots
    int cLane = threadIdx.x & 15;                   // channel within chunk
    int c0 = chunk * CH_PER_BLK;

    for (int p = p0 + tSub; p < p1; p += 16) {
        int pi   = ptIdx[p];
        int cell = sortedCell[p] - segBase;         // 0..511
        float v  = feat[(size_t)pi * C + c0 + cLane];
        int addr = cLane * CELLS_PER_BLK + (cell ^ (cLane << 2));
        atomicMax(&lds[addr], __float_as_int(fmaxf(v, 0.0f)));
    }
    __syncthreads();

    const float* ldsF = reinterpret_cast<const float*>(lds);
    // 16 ch * 512 cells = 2048 float4 = 256 threads * 8
#pragma unroll
    for (int it = 0; it < (CH_PER_BLK * CELLS_PER_BLK / 4) / 256; ++it) {
        int f = threadIdx.x + 256 * it;
        int c = f >> 7;                              // 128 float4 per channel
        int q = f & 127;
        int base = c * CELLS_PER_BLK + ((q * 4) ^ (c << 2));
        float4 v = *reinterpret_cast<const float4*>(ldsF + base);
        size_t ob = ((size_t)(b * C + c0 + c)) * (size_t)WHD
                  + (size_t)cb * CELLS_PER_BLK + q * 4;
        *reinterpret_cast<float4*>(out + ob) = v;
    }
}

extern "C" void kernel_launch(void* const* d_in, const int* in_sizes, int n_in,
                              void* d_out, int out_size, void* d_ws, size_t ws_size,
                              hipStream_t stream)
{
    const float* feat = (const float*)d_in[0];
    const float* pts  = (const float*)d_in[1];

    int BN  = in_sizes[1] / 3;           // B*N
    int C   = in_sizes[0] / BN;          // 256
    const int W = 32, H = 32, Dd = 32;   // fixed by setup_inputs
    int WHD = W * H * Dd;                // 32768
    int B   = out_size / (C * WHD);      // 16
    int N   = BN / B;                    // 8192
    int NSEG = B * WHD;                  // 524288
    int nBlocksScan = (NSEG + 255) / 256;

    char* w = (char*)d_ws;
    auto alloc = [&](size_t bytes) -> void* {
        void* p = (void*)w;
        w += ((bytes + 255) / 256) * 256;
        return p;
    };
    int* cellId     = (int*)alloc((size_t)BN * 4);
    int* counts     = (int*)alloc((size_t)NSEG * 4);
    int* offsets    = (int*)alloc(((size_t)NSEG + 1) * 4);
    int* cur        = (int*)alloc((size_t)NSEG * 4);
    int* blockSums  = (int*)alloc((size_t)nBlocksScan * 4);
    int* ptIdx      = (int*)alloc((size_t)BN * 4);
    int* sortedCell = (int*)alloc((size_t)BN * 4);
    (void)ws_size;

    hipMemsetAsync(counts, 0, (size_t)NSEG * 4, stream);

    k_count<<<(BN + 255) / 256, 256, 0, stream>>>(
        pts, cellId, counts, BN, N, H * Dd, Dd, WHD,
        (float)W, (float)H, (float)Dd, W - 1, H - 1, Dd - 1);

    k_scan1<<<nBlocksScan, 256, 0, stream>>>(counts, offsets, blockSums, NSEG);
    k_scan2<<<1, 256, 0, stream>>>(blockSums, nBlocksScan);
    k_scan3<<<nBlocksScan, 256, 0, stream>>>(offsets, blockSums, cur, NSEG, BN);

    k_scatter<<<(BN + 255) / 256, 256, 0, stream>>>(cellId, cur, ptIdx, sortedCell, BN);

    dim3 g(WHD / CELLS_PER_BLK, C / CH_PER_BLK, B);
    k_pool<<<g, 256, 0, stream>>>(feat, offsets, ptIdx, sortedCell,
                                  (float*)d_out, C, WHD);
}

// Round 3
// 139.783 us; speedup vs baseline: 2.8996x; 2.1060x over previous
//
#include <hip/hip_runtime.h>

// gridPooling: scatter-max of per-point features into a voxel grid.
// CSR binning (count -> scan -> scatter packed int2), then tiled gather-max:
// block = (batch, 512 cells, 16-channel chunk), LDS tile [16][512] with
// float-as-int atomicMax. R3 changes vs R2: 4-deep MLP in the gather loop,
// packed int2 (pi,cell) loads, XCD-aware block swizzle (contiguous write
// regions per XCD), nontemporal float4 stores, int4 LDS zero-init.

#define CELLS_PER_BLK 512
#define CH_PER_BLK    16

typedef float float4v __attribute__((ext_vector_type(4)));
typedef int   int4v   __attribute__((ext_vector_type(4)));

__global__ __launch_bounds__(256) void k_count(
    const float* __restrict__ pts, int* __restrict__ cellId,
    int* __restrict__ counts, int BN, int N, int HD, int Dd, int WHD,
    float fW, float fH, float fD, int Wm1, int Hm1, int Dm1)
{
    int i = blockIdx.x * 256 + threadIdx.x;
    if (i >= BN) return;
    float x = pts[3 * i + 0];
    float y = pts[3 * i + 1];
    float z = pts[3 * i + 2];
    int ix = (int)floorf(x * fW); ix = ix < 0 ? 0 : (ix > Wm1 ? Wm1 : ix);
    int iy = (int)floorf(y * fH); iy = iy < 0 ? 0 : (iy > Hm1 ? Hm1 : iy);
    int iz = (int)floorf(z * fD); iz = iz < 0 ? 0 : (iz > Dm1 ? Dm1 : iz);
    int b = i / N;
    int seg = b * WHD + ix * HD + iy * Dd + iz;
    cellId[i] = seg;
    atomicAdd(&counts[seg], 1);
}

// Block-local exclusive scan (256 elems/block); block totals to blockSums.
__global__ __launch_bounds__(256) void k_scan1(
    const int* __restrict__ counts, int* __restrict__ excl,
    int* __restrict__ blockSums, int n)
{
    __shared__ int lds[256];
    int tid = threadIdx.x;
    int i = blockIdx.x * 256 + tid;
    int v = (i < n) ? counts[i] : 0;
    lds[tid] = v;
    __syncthreads();
    for (int off = 1; off < 256; off <<= 1) {
        int t = (tid >= off) ? lds[tid - off] : 0;
        __syncthreads();
        lds[tid] += t;
        __syncthreads();
    }
    int incl = lds[tid];
    if (i < n) excl[i] = incl - v;
    if (tid == 255) blockSums[blockIdx.x] = incl;
}

// Single-block exclusive scan of block sums (serial over 256-wide chunks).
__global__ __launch_bounds__(256) void k_scan2(int* __restrict__ blockSums, int nb)
{
    __shared__ int lds[256];
    __shared__ int carryS;
    int tid = threadIdx.x;
    if (tid == 0) carryS = 0;
    __syncthreads();
    int nChunks = (nb + 255) / 256;
    for (int ch = 0; ch < nChunks; ++ch) {
        int i = ch * 256 + tid;
        int v = (i < nb) ? blockSums[i] : 0;
        lds[tid] = v;
        __syncthreads();
        for (int off = 1; off < 256; off <<= 1) {
            int t = (tid >= off) ? lds[tid - off] : 0;
            __syncthreads();
            lds[tid] += t;
            __syncthreads();
        }
        int incl = lds[tid];
        int base = carryS;
        __syncthreads();               // everyone read carryS before update
        if (i < nb) blockSums[i] = base + incl - v;
        if (tid == 255) carryS = base + incl;
        __syncthreads();
    }
}

__global__ __launch_bounds__(256) void k_scan3(
    int* __restrict__ excl, const int* __restrict__ blockSums,
    int* __restrict__ cur, int n, int total)
{
    int i = blockIdx.x * 256 + threadIdx.x;
    if (i < n) {
        int o = excl[i] + blockSums[blockIdx.x];
        excl[i] = o;
        cur[i] = o;
    }
    if (i == 0) excl[n] = total;
}

__global__ __launch_bounds__(256) void k_scatter(
    const int* __restrict__ cellId, int* __restrict__ cur,
    int2* __restrict__ ptCell, int BN)
{
    int i = blockIdx.x * 256 + threadIdx.x;
    if (i >= BN) return;
    int seg = cellId[i];
    int pos = atomicAdd(&cur[seg], 1);
    ptCell[pos] = make_int2(i, seg);   // (feat row, cell id), CSR-sorted
}

// Block = (cellBlock of 512 cells, 16-channel chunk, batch), via XCD swizzle.
// Gather: 16-lane subgroups read 16 consecutive channels per point; 4-deep
// software pipeline (4 independent ptCell+feat loads, then 4 LDS atomics).
// Float-as-int atomicMax exact for values clamped to >= 0. XOR swizzle
// (cell ^ (cLane<<2)) breaks bank conflicts. Write-out: nontemporal float4,
// 2KB contiguous per channel, XCD-grouped regions.
__global__ __launch_bounds__(256, 5) void k_pool(
    const float* __restrict__ feat, const int* __restrict__ offsets,
    const int2* __restrict__ ptCell, float* __restrict__ out,
    int C, int WHD, int nCb, int nChunk)
{
    __shared__ int lds[CH_PER_BLK * CELLS_PER_BLK];

    // XCD-aware swizzle: XCD x (= lin%8) gets a contiguous slice of the
    // linear (cb, chunk, b) space -> long sequential write streams per L2.
    int lin = blockIdx.x;
    int nwg = gridDim.x;               // multiple of 8 here (16384)
    int swz = (lin & 7) * (nwg >> 3) + (lin >> 3);
    int cb    = swz % nCb;
    int rest  = swz / nCb;
    int chunk = rest % nChunk;
    int b     = rest / nChunk;

    int segBase = b * WHD + cb * CELLS_PER_BLK;
    int c0 = chunk * CH_PER_BLK;

    int4v* l4 = reinterpret_cast<int4v*>(lds);
    int4v zero = {0, 0, 0, 0};
#pragma unroll
    for (int it = 0; it < (CH_PER_BLK * CELLS_PER_BLK / 4) / 256; ++it)
        l4[threadIdx.x + 256 * it] = zero;
    __syncthreads();

    int p0 = offsets[segBase];                 // block-uniform -> scalar
    int p1 = offsets[segBase + CELLS_PER_BLK];
    int tSub  = threadIdx.x >> 4;              // 16 point slots
    int cLane = threadIdx.x & 15;              // channel within chunk
    const float* fbase = feat + c0 + cLane;

    for (int pb = p0 + tSub; pb < p1; pb += 64) {
        int2  pc[4];
        float v[4];
#pragma unroll
        for (int k = 0; k < 4; ++k) {
            int p  = pb + 16 * k;
            int pp = p < p1 ? p : p1 - 1;      // clamped: loads always valid
            pc[k] = ptCell[pp];
        }
#pragma unroll
        for (int k = 0; k < 4; ++k)
            v[k] = fbase[(size_t)pc[k].x * C];
#pragma unroll
        for (int k = 0; k < 4; ++k) {
            if (pb + 16 * k < p1) {
                int cell = pc[k].y - segBase;  // 0..511
                int addr = cLane * CELLS_PER_BLK + (cell ^ (cLane << 2));
                atomicMax(&lds[addr], __float_as_int(fmaxf(v[k], 0.0f)));
            }
        }
    }
    __syncthreads();

    const float* ldsF = reinterpret_cast<const float*>(lds);
    // 16 ch * 512 cells = 2048 float4 = 256 threads * 8
#pragma unroll
    for (int it = 0; it < (CH_PER_BLK * CELLS_PER_BLK / 4) / 256; ++it) {
        int f = threadIdx.x + 256 * it;
        int c = f >> 7;                        // 128 float4 per channel
        int q = f & 127;
        int base = c * CELLS_PER_BLK + ((q * 4) ^ (c << 2));
        float4v v = *reinterpret_cast<const float4v*>(ldsF + base);
        size_t ob = ((size_t)(b * C + c0 + c)) * (size_t)WHD
                  + (size_t)cb * CELLS_PER_BLK + q * 4;
        __builtin_nontemporal_store(v, reinterpret_cast<float4v*>(out + ob));
    }
}

extern "C" void kernel_launch(void* const* d_in, const int* in_sizes, int n_in,
                              void* d_out, int out_size, void* d_ws, size_t ws_size,
                              hipStream_t stream)
{
    const float* feat = (const float*)d_in[0];
    const float* pts  = (const float*)d_in[1];

    int BN  = in_sizes[1] / 3;           // B*N
    int C   = in_sizes[0] / BN;          // 256
    const int W = 32, H = 32, Dd = 32;   // fixed by setup_inputs
    int WHD = W * H * Dd;                // 32768
    int B   = out_size / (C * WHD);      // 16
    int N   = BN / B;                    // 8192
    int NSEG = B * WHD;                  // 524288
    int nBlocksScan = (NSEG + 255) / 256;

    char* w = (char*)d_ws;
    auto alloc = [&](size_t bytes) -> void* {
        void* p = (void*)w;
        w += ((bytes + 255) / 256) * 256;
        return p;
    };
    int*  cellId    = (int*)alloc((size_t)BN * 4);
    int*  counts    = (int*)alloc((size_t)NSEG * 4);
    int*  offsets   = (int*)alloc(((size_t)NSEG + 1) * 4);
    int*  cur       = (int*)alloc((size_t)NSEG * 4);
    int*  blockSums = (int*)alloc((size_t)nBlocksScan * 4);
    int2* ptCell    = (int2*)alloc((size_t)BN * 8);
    (void)ws_size;

    hipMemsetAsync(counts, 0, (size_t)NSEG * 4, stream);

    k_count<<<(BN + 255) / 256, 256, 0, stream>>>(
        pts, cellId, counts, BN, N, H * Dd, Dd, WHD,
        (float)W, (float)H, (float)Dd, W - 1, H - 1, Dd - 1);

    k_scan1<<<nBlocksScan, 256, 0, stream>>>(counts, offsets, blockSums, NSEG);
    k_scan2<<<1, 256, 0, stream>>>(blockSums, nBlocksScan);
    k_scan3<<<nBlocksScan, 256, 0, stream>>>(offsets, blockSums, cur, NSEG, BN);

    k_scatter<<<(BN + 255) / 256, 256, 0, stream>>>(cellId, cur, ptCell, BN);

    int nCb = WHD / CELLS_PER_BLK;       // 64
    int nChunk = C / CH_PER_BLK;         // 16
    int nwg = nCb * nChunk * B;          // 16384
    k_pool<<<nwg, 256, 0, stream>>>(feat, offsets, ptCell,
                                    (float*)d_out, C, WHD, nCb, nChunk);
}